// Round 8
// baseline (57.929 us; speedup 1.0000x reference)
//
#include <hip/hip_runtime.h>

// LIF spike recurrence over time axis.
// x: [B=32, T=10, C=128, H=32, W=32] fp32 -> spikes same shape fp32.
// mem_t = tau*mem_{t-1} + x_t; spike = (mem_t > thresh); mem_t <- (1-spike)*mem_t.
//
// R8: software-pipelined prefetch depth 5 (vs R7's all-10-loads-first).
// Keeps 5 nt-loads outstanding at all times but halves live data VGPRs
// (~20-24 vs 40) -> below the 64-VGPR occupancy step, max waves/SIMD,
// and interleaves the store stream with the remaining loads.
// Per-instruction fully coalesced, nt load/store, 4096 blocks.

typedef float f32x4 __attribute__((ext_vector_type(4)));

#define LIF_T 10
#define LIF_PF 5               // prefetch depth
#define LIF_INNER4 32768       // C*H*W/4 per (b,t) slab, in float4 units
#define LIF_TAU 0.5f
#define LIF_THRESH 1.0f

__global__ void __launch_bounds__(256) lif_kernel(const f32x4* __restrict__ x,
                                                  f32x4* __restrict__ y) {
    const int i = blockIdx.x * blockDim.x + threadIdx.x;   // 0 .. INNER4-1
    const int b = blockIdx.y;
    const size_t base = (size_t)b * LIF_T * LIF_INNER4 + i;

    // rolling prefetch buffer, statically indexed (full unroll => registers)
    f32x4 xv[LIF_PF];
#pragma unroll
    for (int t = 0; t < LIF_PF; ++t) {
        xv[t] = __builtin_nontemporal_load(&x[base + (size_t)t * LIF_INNER4]);
    }

    f32x4 m = (f32x4)(0.f);
#pragma unroll
    for (int t = 0; t < LIF_T; ++t) {
        f32x4 cur = xv[t % LIF_PF];            // t%PF is compile-time constant
        if (t + LIF_PF < LIF_T) {
            xv[t % LIF_PF] = __builtin_nontemporal_load(
                &x[base + (size_t)(t + LIF_PF) * LIF_INNER4]);
        }

        m = m * LIF_TAU + cur;

        f32x4 s;
        s.x = (m.x > LIF_THRESH) ? 1.f : 0.f;
        s.y = (m.y > LIF_THRESH) ? 1.f : 0.f;
        s.z = (m.z > LIF_THRESH) ? 1.f : 0.f;
        s.w = (m.w > LIF_THRESH) ? 1.f : 0.f;

        __builtin_nontemporal_store(s, &y[base + (size_t)t * LIF_INNER4]);

        m.x = (s.x > 0.f) ? 0.f : m.x;
        m.y = (s.y > 0.f) ? 0.f : m.y;
        m.z = (s.z > 0.f) ? 0.f : m.z;
        m.w = (s.w > 0.f) ? 0.f : m.w;
    }
}

extern "C" void kernel_launch(void* const* d_in, const int* in_sizes, int n_in,
                              void* d_out, int out_size, void* d_ws, size_t ws_size,
                              hipStream_t stream) {
    const f32x4* x = (const f32x4*)d_in[0];
    f32x4* y = (f32x4*)d_out;

    dim3 block(256, 1, 1);
    dim3 grid(LIF_INNER4 / 256, 32, 1);   // 128 x 32 = 4096 blocks
    lif_kernel<<<grid, block, 0, stream>>>(x, y);
}